// Round 4
// baseline (172.048 us; speedup 1.0000x reference)
//
#include <hip/hip_runtime.h>
#include <hip/hip_cooperative_groups.h>

namespace cg = cooperative_groups;

#define NB 64
#define NK 49
#define NL 200
#define ND 36
#define LD (NL*ND)              // 7200
#define NCH 16                  // l-chunks

// workspace layout (float offsets)
#define AT_FLOATS  (LD*NB*4)                    // At[ld][b][4] = {x,t,m,pd}
#define WPK_FLOATS (LD*NK*6)                    // Wpk[ld][k][6] = {wt0..3, 4*bt, wv}
#define PART_FLOATS ((size_t)ND*NCH*NK*NB)      // part[d][c][k][b]
#define WPK_OFF   AT_FLOATS
#define PART_OFF  (AT_FLOATS + WPK_FLOATS)
#define WS_FULL_BYTES ((size_t)(AT_FLOATS + WPK_FLOATS + PART_FLOATS) * 4)

#define LOG2E 1.44269504088896f

#if __has_builtin(__builtin_amdgcn_exp2f)
#define EXP2F(x) __builtin_amdgcn_exp2f(x)
#else
#define EXP2F(x) __expf((x) * 0.6931471805599453f)
#endif

// =================== single cooperative kernel: pack -> compute -> reduce ===================
__global__ __launch_bounds__(512, 4) void alnn_coop(
    const float* __restrict__ X, const float* __restrict__ T,
    const float* __restrict__ M, const float* __restrict__ PD,
    const float* __restrict__ alpha, const float* __restrict__ w_v,
    const float4* __restrict__ w_t, const float* __restrict__ b_v,
    const float* __restrict__ b_t, float* __restrict__ out,
    float* __restrict__ ws)
{
    __shared__ float tile[9440];
    const int bid = blockIdx.x, t = threadIdx.x;
    float* part = ws + PART_OFF;

    // ---------------- P1: pack (450 tile-jobs over 512 blocks) ----------------
    if (bid < 225) {
        // activations: 32 ld x 64 b x {X,T,M,PD} -> At[ld][b][4]; LDS [a][b][33]
        const int ld0 = bid * 32;
        const int ld = t & 31, bq = t >> 5;          // bq 0..15
        const float* srcs[4] = {X, T, M, PD};
        #pragma unroll
        for (int a = 0; a < 4; a++) {
            const float* A = srcs[a];
            #pragma unroll
            for (int b = bq; b < 64; b += 16)
                tile[(a * 64 + b) * 33 + ld] = A[(size_t)b * LD + ld0 + ld];
        }
        __syncthreads();
        float4* At4w = (float4*)ws;
        const int b = t & 63, ldq = t >> 6;          // ldq 0..7
        #pragma unroll
        for (int r = 0; r < 4; r++) {
            const int l = ldq * 4 + r;
            float4 v;
            v.x = tile[(0 * 64 + b) * 33 + l];
            v.y = tile[(1 * 64 + b) * 33 + l];
            v.z = tile[(2 * 64 + b) * 33 + l];
            v.w = tile[(3 * 64 + b) * 33 + l];
            At4w[(size_t)(ld0 + l) * 64 + b] = v;
        }
    } else if (bid < 450) {
        // weights: 32 ld x 49 k -> Wpk[ld][k][6]; LDS [ld][295] (odd stride)
        const int ld0 = (bid - 225) * 32;
        const int ld = t & 31, kq = t >> 5;          // kq 0..15
        for (int k = kq; k < NK; k += 16) {
            const float4 wt = w_t[(size_t)k * LD + ld0 + ld];
            const float  bt = b_t[(size_t)k * LD + ld0 + ld];
            const float  wv = w_v[(size_t)k * LD + ld0 + ld];
            float* w = tile + ld * 295 + k * 6;
            w[0] = wt.x; w[1] = wt.y; w[2] = wt.z; w[3] = wt.w;
            w[4] = 4.0f * bt; w[5] = wv;
        }
        __syncthreads();
        float* dst = ws + WPK_OFF + (size_t)ld0 * 294;
        for (int i = t; i < 32 * 294; i += 512) {
            const int l = i / 294, r = i - l * 294;
            dst[i] = tile[l * 295 + r];
        }
    }

    cg::this_grid().sync();

    // ---------------- P2: fused compute (4032 wave-jobs over 4096 wave slots) -------------
    {
        const int w = t >> 6, b = t & 63;
        const int wjob = bid * 8 + w;                // consecutive jobs share (d,c) -> L1 reuse
        if (wjob < 36 * NCH * 7) {
            const int ks = wjob % 7, t2 = wjob / 7;
            const int d = t2 % 36, c = t2 / 36;
            const int len = (c < 8) ? 13 : 12;
            const int l0  = (c < 8) ? 13 * c : 104 + 12 * (c - 8);
            const int k0  = __builtin_amdgcn_readfirstlane(ks * 7);

            float arn[7], rk[7];
            #pragma unroll
            for (int kk = 0; kk < 7; kk++) {
                arn[kk] = -fmaxf(alpha[k0 + kk], 0.0f) * LOG2E;
                rk[kk]  = (float)(k0 + kk);
            }

            const float4* At4 = (const float4*)ws;
            const float*  Wpk = ws + WPK_OFF;
            float acc[7] = {0, 0, 0, 0, 0, 0, 0};

            for (int ll = 0; ll < len; ll++) {
                const int ld = (l0 + ll) * ND + d;
                const float4 av = At4[(size_t)ld * 64 + b];
                const float xp = fmaxf(av.x, 0.0f);      // relu(x*e) == relu(x)*e
                const float* wr = Wpk + (size_t)ld * 294 + k0 * 6;
                #pragma unroll
                for (int kk = 0; kk < 7; kk++) {
                    const float dist = fabsf(av.y - rk[kk]);
                    const float e    = EXP2F(arn[kk] * dist);
                    float s = fmaf(wr[kk*6+0], av.x,
                              fmaf(wr[kk*6+1], xp * e,
                              fmaf(wr[kk*6+2], av.z,
                              fmaf(wr[kk*6+3], av.w, wr[kk*6+4]))));
                    acc[kk] = fmaf(wr[kk*6+5], fmaxf(s, 0.0f), acc[kk]);
                }
            }
            #pragma unroll
            for (int kk = 0; kk < 7; kk++)
                part[((size_t)(d * NCH + c) * NK + (k0 + kk)) * 64 + b] = acc[kk];
        }
    }

    cg::this_grid().sync();

    // ---------------- P3: reduce chunks + bias + relu (1764 wave-jobs) ---------------------
    {
        const int w = t >> 6, b = t & 63;
        const int widx = bid * 8 + w;
        if (widx < ND * NK) {
            const int d = widx / NK, k = widx - d * NK;
            float sum = 0.0f;
            #pragma unroll
            for (int c = 0; c < NCH; c++)
                sum += part[((size_t)(d * NCH + c) * NK + k) * 64 + b];
            out[((size_t)b * NK + k) * ND + d] =
                fmaxf(sum + 200.0f * b_v[k * ND + d], 0.0f);
        }
    }
}

// =================== fallback: proven 3-kernel path (round-3) ===============================
__global__ __launch_bounds__(256) void alnn_pack(
    const float* __restrict__ X, const float* __restrict__ T,
    const float* __restrict__ M, const float* __restrict__ PD,
    const float* __restrict__ w_v, const float4* __restrict__ w_t,
    const float* __restrict__ b_t, float* __restrict__ ws)
{
    __shared__ float tile[9440];
    const int bid = blockIdx.x, t = threadIdx.x;

    if (bid < 225) {
        const int ld0 = bid * 32;
        const int ld = t & 31, bq = t >> 5;
        const float* src[4] = {X, T, M, PD};
        #pragma unroll
        for (int a = 0; a < 4; a++) {
            const float* A = src[a];
            for (int b = bq; b < 64; b += 8)
                tile[(a * 64 + b) * 33 + ld] = A[b * LD + ld0 + ld];
        }
        __syncthreads();
        float4* At4 = (float4*)ws;
        const int b = t & 63, ldq = t >> 6;
        #pragma unroll
        for (int r = 0; r < 8; r++) {
            const int l = ldq * 8 + r;
            float4 v;
            v.x = tile[(0 * 64 + b) * 33 + l];
            v.y = tile[(1 * 64 + b) * 33 + l];
            v.z = tile[(2 * 64 + b) * 33 + l];
            v.w = tile[(3 * 64 + b) * 33 + l];
            At4[(size_t)(ld0 + l) * 64 + b] = v;
        }
    } else {
        const int ld0 = (bid - 225) * 32;
        const int ld = t & 31, kq = t >> 5;
        for (int k = kq; k < NK; k += 8) {
            const float4 wt = w_t[(size_t)k * LD + ld0 + ld];
            const float  bt = b_t[(size_t)k * LD + ld0 + ld];
            const float  wv = w_v[(size_t)k * LD + ld0 + ld];
            float* w = tile + ld * 295 + k * 6;
            w[0] = wt.x; w[1] = wt.y; w[2] = wt.z; w[3] = wt.w;
            w[4] = 4.0f * bt; w[5] = wv;
        }
        __syncthreads();
        float* Wpk = ws + WPK_OFF + (size_t)ld0 * (NK * 6);
        for (int i = t; i < 32 * NK * 6; i += 256) {
            const int l = i / (NK * 6), r = i - l * (NK * 6);
            Wpk[i] = tile[l * 295 + r];
        }
    }
}

__global__ __launch_bounds__(512) void alnn_main(
    const float* __restrict__ ws_ro, const float* __restrict__ alpha,
    float* __restrict__ part)
{
    const int bid = blockIdx.x, t = threadIdx.x;
    const int d = bid % ND, c = bid / ND;
    const int len = (c < 8) ? 13 : 12;
    const int l0  = (c < 8) ? 13 * c : 104 + 12 * (c - 8);
    const int b = t & 63;
    const int k0 = __builtin_amdgcn_readfirstlane((t >> 6) * 6);
    const int nk = (k0 == 42) ? 7 : 6;

    const float4* At4 = (const float4*)ws_ro;
    const float*  Wpk = ws_ro + WPK_OFF;

    float arn[7], rk[7];
    #pragma unroll
    for (int kk = 0; kk < 7; kk++) {
        arn[kk] = -fmaxf(alpha[k0 + kk], 0.0f) * LOG2E;
        rk[kk]  = (float)(k0 + kk);
    }

    float acc[7] = {0, 0, 0, 0, 0, 0, 0};

    for (int ll = 0; ll < len; ll++) {
        const int ld = (l0 + ll) * ND + d;
        const float4 av = At4[(size_t)ld * 64 + b];
        const float xp = fmaxf(av.x, 0.0f);
        const float* wr = Wpk + ((size_t)ld * NK + k0) * 6;
        #pragma unroll
        for (int kk = 0; kk < 7; kk++) {
            if (kk < 6 || nk == 7) {
                const float dist = fabsf(av.y - rk[kk]);
                const float e    = EXP2F(arn[kk] * dist);
                float s = fmaf(wr[kk*6+0], av.x,
                          fmaf(wr[kk*6+1], xp * e,
                          fmaf(wr[kk*6+2], av.z,
                          fmaf(wr[kk*6+3], av.w, wr[kk*6+4]))));
                acc[kk] = fmaf(wr[kk*6+5], fmaxf(s, 0.0f), acc[kk]);
            }
        }
    }

    #pragma unroll
    for (int kk = 0; kk < 7; kk++)
        if (kk < nk)
            part[(((size_t)d * NCH + c) * NK + (k0 + kk)) * 64 + b] = acc[kk];
}

__global__ __launch_bounds__(256) void alnn_reduce(
    const float* __restrict__ part, const float* __restrict__ b_v,
    float* __restrict__ out)
{
    const int bid = blockIdx.x, t = threadIdx.x;
    const int d = bid >> 3, oct = bid & 7;
    for (int j = t; j < NK * 8; j += 256) {
        const int k = j >> 3, b = oct * 8 + (j & 7);
        float sum = 0.0f;
        #pragma unroll
        for (int cc = 0; cc < NCH; cc++)
            sum += part[(((size_t)d * NCH + cc) * NK + k) * 64 + b];
        out[(b * NK + k) * ND + d] = fmaxf(sum + 200.0f * b_v[k * ND + d], 0.0f);
    }
}

// legacy single-kernel fallback (round-1, proven)
__global__ __launch_bounds__(256) void alnn_fused_kernel(
    const float* __restrict__ X, const float* __restrict__ T,
    const float* __restrict__ M, const float* __restrict__ PD,
    const float* __restrict__ alpha, const float* __restrict__ w_v,
    const float4* __restrict__ w_t, const float* __restrict__ b_v,
    const float* __restrict__ b_t, float* __restrict__ out)
{
    const int bk = blockIdx.x;
    const int k  = bk % NK;
    const int b  = bk / NK;
    const int t  = threadIdx.x;

    __shared__ float part[7][ND];

    const float alpha_k = fmaxf(alpha[k], 0.0f);
    const float refk    = (float)k;

    if (t < 7 * ND) {
        const int d = t % ND;
        const int j = t / ND;
        const float*  Xp  = X   + (size_t)b * LD + d;
        const float*  Tp  = T   + (size_t)b * LD + d;
        const float*  Mp  = M   + (size_t)b * LD + d;
        const float*  Pp  = PD  + (size_t)b * LD + d;
        const float*  wvp = w_v + (size_t)k * LD + d;
        const float*  btp = b_t + (size_t)k * LD + d;
        const float4* wtp = w_t + (size_t)k * LD + d;

        float acc = 0.0f;
        for (int l = j; l < NL; l += 7) {
            const int o = l * ND;
            const float x  = Xp[o];
            const float tt = Tp[o];
            const float m  = Mp[o];
            const float pd = Pp[o];
            const float4 w = wtp[o];
            const float bt = btp[o];
            const float dist  = fabsf(tt - refk);
            const float e     = __expf(-alpha_k * dist);
            const float inten = fmaxf(x * e, 0.0f);
            float s = fmaf(w.x, x, fmaf(w.y, inten, fmaf(w.z, m, fmaf(w.w, pd, 4.0f * bt))));
            s = fmaxf(s, 0.0f);
            acc = fmaf(wvp[o], s, acc);
        }
        part[j][d] = acc;
    }
    __syncthreads();

    if (t < ND) {
        float sum = 0.0f;
        #pragma unroll
        for (int j = 0; j < 7; ++j) sum += part[j][t];
        sum += (float)NL * b_v[k * ND + t];
        out[(size_t)bk * ND + t] = fmaxf(sum, 0.0f);
    }
}

extern "C" void kernel_launch(void* const* d_in, const int* in_sizes, int n_in,
                              void* d_out, int out_size, void* d_ws, size_t ws_size,
                              hipStream_t stream) {
    const float* X     = (const float*)d_in[0];
    const float* T     = (const float*)d_in[1];
    const float* M     = (const float*)d_in[2];
    const float* PD    = (const float*)d_in[3];
    const float* alpha = (const float*)d_in[4];
    const float* w_v   = (const float*)d_in[5];
    const float* w_t   = (const float*)d_in[6];
    const float* b_v   = (const float*)d_in[7];
    const float* b_t   = (const float*)d_in[8];
    float* out = (float*)d_out;
    float* ws  = (float*)d_ws;

    if (ws_size >= WS_FULL_BYTES) {
        // try single cooperative kernel first
        const float4* w_t4 = (const float4*)w_t;
        void* args[] = {(void*)&X, (void*)&T, (void*)&M, (void*)&PD, (void*)&alpha,
                        (void*)&w_v, (void*)&w_t4, (void*)&b_v, (void*)&b_t,
                        (void*)&out, (void*)&ws};
        hipError_t e = hipLaunchCooperativeKernel((void*)alnn_coop, dim3(512), dim3(512),
                                                  args, 0, stream);
        if (e == hipSuccess) return;

        // fallback: proven 3-kernel path
        alnn_pack<<<450, 256, 0, stream>>>(X, T, M, PD, w_v, (const float4*)w_t, b_t, ws);
        alnn_main<<<ND * NCH, 512, 0, stream>>>(ws, alpha, ws + PART_OFF);
        alnn_reduce<<<288, 256, 0, stream>>>(ws + PART_OFF, b_v, out);
    } else {
        alnn_fused_kernel<<<NB * NK, 256, 0, stream>>>(
            X, T, M, PD, alpha, w_v, (const float4*)w_t, b_v, b_t, out);
    }
}

// Round 5
// 30.758 us; speedup vs baseline: 5.5936x; 5.5936x over previous
//
#include <hip/hip_runtime.h>

#define NB 64
#define NK 49
#define NL 200
#define ND 36
#define LD (NL*ND)              // 7200

// workspace layout (float offsets)
#define AT_FLOATS  (LD*NB*4)                    // At[ld][b][4] = {x,t,m,pd}
#define WPK_FLOATS (LD*NK*6)                    // Wpk[ld][k][6] = {wt0..3, 4*bt, wv}
#define WPK_OFF   AT_FLOATS
#define WS_PACK_BYTES ((size_t)(AT_FLOATS + WPK_FLOATS) * 4)

#define LOG2E 1.44269504088896f

#if __has_builtin(__builtin_amdgcn_exp2f)
#define EXP2F(x) __builtin_amdgcn_exp2f(x)
#else
#define EXP2F(x) __expf((x) * 0.6931471805599453f)
#endif

// ---------------- K1: LDS-transposed packs (coalesced on both sides) ----------------------
__global__ __launch_bounds__(256) void alnn_pack(
    const float* __restrict__ X, const float* __restrict__ T,
    const float* __restrict__ M, const float* __restrict__ PD,
    const float* __restrict__ w_v, const float4* __restrict__ w_t,
    const float* __restrict__ b_t, float* __restrict__ ws)
{
    __shared__ float tile[9440];
    const int bid = blockIdx.x, t = threadIdx.x;

    if (bid < 225) {
        // activations: 32 ld x 64 b x {X,T,M,PD} -> At[ld][b][4]; LDS [a][b][33]
        const int ld0 = bid * 32;
        const int ld = t & 31, bq = t >> 5;
        const float* src[4] = {X, T, M, PD};
        #pragma unroll
        for (int a = 0; a < 4; a++) {
            const float* A = src[a];
            for (int b = bq; b < 64; b += 8)
                tile[(a * 64 + b) * 33 + ld] = A[(size_t)b * LD + ld0 + ld];
        }
        __syncthreads();
        float4* At4 = (float4*)ws;
        const int b = t & 63, ldq = t >> 6;
        #pragma unroll
        for (int r = 0; r < 8; r++) {
            const int l = ldq * 8 + r;
            float4 v;
            v.x = tile[(0 * 64 + b) * 33 + l];
            v.y = tile[(1 * 64 + b) * 33 + l];
            v.z = tile[(2 * 64 + b) * 33 + l];
            v.w = tile[(3 * 64 + b) * 33 + l];
            At4[(size_t)(ld0 + l) * 64 + b] = v;
        }
    } else {
        // weights: 32 ld x 49 k -> Wpk[ld][k][6]; LDS [ld][295] (odd stride)
        const int ld0 = (bid - 225) * 32;
        const int ld = t & 31, kq = t >> 5;
        for (int k = kq; k < NK; k += 8) {
            const float4 wt = w_t[(size_t)k * LD + ld0 + ld];
            const float  bt = b_t[(size_t)k * LD + ld0 + ld];
            const float  wv = w_v[(size_t)k * LD + ld0 + ld];
            float* w = tile + ld * 295 + k * 6;
            w[0] = wt.x; w[1] = wt.y; w[2] = wt.z; w[3] = wt.w;
            w[4] = 4.0f * bt; w[5] = wv;
        }
        __syncthreads();
        float* Wpk = ws + WPK_OFF + (size_t)ld0 * 294;
        for (int i = t; i < 32 * 294; i += 256) {
            const int l = i / 294, r = i - l * 294;
            Wpk[i] = tile[l * 295 + r];
        }
    }
}

// ---------------- K2: fused compute + cross-wave reduce + bias + relu ---------------------
// grid 252 = (d:36) x (ks:7); block 512 = 8 waves; lane=b; wave covers 25 l's x 7 k's.
__global__ __launch_bounds__(512) void alnn_main2(
    const float* __restrict__ ws_ro, const float* __restrict__ alpha,
    const float* __restrict__ b_v, float* __restrict__ out)
{
    __shared__ float red[8 * 7 * 64];                    // 14336 B

    // bijective chunked XCD swizzle (nwg=252: q=31, r=4) so the 7 ks-blocks of one d
    // land on the same XCD -> At d-slice fetched into one L2 once.
    const int orig = blockIdx.x;
    const int xcd  = orig & 7, slot = orig >> 3;
    const int base = (xcd < 4) ? xcd * 32 : 128 + (xcd - 4) * 31;
    const int job  = base + slot;

    const int d  = job / 7, ks = job - (job / 7) * 7;
    const int t  = threadIdx.x;
    const int b  = t & 63;
    const int w  = __builtin_amdgcn_readfirstlane(t >> 6);   // wave id 0..7, force SGPR
    const int k0 = ks * 7;

    const float4* At4 = (const float4*)ws_ro;
    const float*  Wpk = ws_ro + WPK_OFF;

    float arn[7], rk[7];
    #pragma unroll
    for (int kk = 0; kk < 7; kk++) {
        arn[kk] = -fmaxf(alpha[k0 + kk], 0.0f) * LOG2E;
        rk[kk]  = (float)(k0 + kk);
    }

    float acc[7] = {0, 0, 0, 0, 0, 0, 0};

    const int lbeg = w * 25;
    #pragma unroll 5
    for (int ll = 0; ll < 25; ll++) {
        const int ld = (lbeg + ll) * ND + d;
        const float4 av = At4[(size_t)ld * 64 + b];
        const float xp = fmaxf(av.x, 0.0f);              // relu(x*e) == relu(x)*e, e>0
        const float* wr = Wpk + (size_t)ld * 294 + k0 * 6;
        #pragma unroll
        for (int kk = 0; kk < 7; kk++) {
            const float dist = fabsf(av.y - rk[kk]);
            const float e    = EXP2F(arn[kk] * dist);
            float s = fmaf(wr[kk*6+0], av.x,
                      fmaf(wr[kk*6+1], xp * e,
                      fmaf(wr[kk*6+2], av.z,
                      fmaf(wr[kk*6+3], av.w, wr[kk*6+4]))));
            acc[kk] = fmaf(wr[kk*6+5], fmaxf(s, 0.0f), acc[kk]);
        }
    }

    #pragma unroll
    for (int kk = 0; kk < 7; kk++)
        red[(w * 7 + kk) * 64 + b] = acc[kk];
    __syncthreads();

    if (w < 7) {
        const int kk = w, k = k0 + kk;
        float sum = 0.0f;
        #pragma unroll
        for (int ww = 0; ww < 8; ww++)
            sum += red[(ww * 7 + kk) * 64 + b];
        out[((size_t)b * NK + k) * ND + d] =
            fmaxf(sum + 200.0f * b_v[k * ND + d], 0.0f);
    }
}

// ---------------- legacy fallback (proven round-1 kernel) ----------------------------------
__global__ __launch_bounds__(256) void alnn_fused_kernel(
    const float* __restrict__ X, const float* __restrict__ T,
    const float* __restrict__ M, const float* __restrict__ PD,
    const float* __restrict__ alpha, const float* __restrict__ w_v,
    const float4* __restrict__ w_t, const float* __restrict__ b_v,
    const float* __restrict__ b_t, float* __restrict__ out)
{
    const int bk = blockIdx.x;
    const int k  = bk % NK;
    const int b  = bk / NK;
    const int t  = threadIdx.x;

    __shared__ float part[7][ND];

    const float alpha_k = fmaxf(alpha[k], 0.0f);
    const float refk    = (float)k;

    if (t < 7 * ND) {
        const int d = t % ND;
        const int j = t / ND;
        const float*  Xp  = X   + (size_t)b * LD + d;
        const float*  Tp  = T   + (size_t)b * LD + d;
        const float*  Mp  = M   + (size_t)b * LD + d;
        const float*  Pp  = PD  + (size_t)b * LD + d;
        const float*  wvp = w_v + (size_t)k * LD + d;
        const float*  btp = b_t + (size_t)k * LD + d;
        const float4* wtp = w_t + (size_t)k * LD + d;

        float acc = 0.0f;
        for (int l = j; l < NL; l += 7) {
            const int o = l * ND;
            const float x  = Xp[o];
            const float tt = Tp[o];
            const float m  = Mp[o];
            const float pd = Pp[o];
            const float4 wv4 = wtp[o];
            const float bt = btp[o];
            const float dist  = fabsf(tt - refk);
            const float e     = __expf(-alpha_k * dist);
            const float inten = fmaxf(x * e, 0.0f);
            float s = fmaf(wv4.x, x, fmaf(wv4.y, inten, fmaf(wv4.z, m, fmaf(wv4.w, pd, 4.0f * bt))));
            s = fmaxf(s, 0.0f);
            acc = fmaf(wvp[o], s, acc);
        }
        part[j][d] = acc;
    }
    __syncthreads();

    if (t < ND) {
        float sum = 0.0f;
        #pragma unroll
        for (int j = 0; j < 7; ++j) sum += part[j][t];
        sum += (float)NL * b_v[k * ND + t];
        out[(size_t)bk * ND + t] = fmaxf(sum, 0.0f);
    }
}

extern "C" void kernel_launch(void* const* d_in, const int* in_sizes, int n_in,
                              void* d_out, int out_size, void* d_ws, size_t ws_size,
                              hipStream_t stream) {
    const float* X     = (const float*)d_in[0];
    const float* T     = (const float*)d_in[1];
    const float* M     = (const float*)d_in[2];
    const float* PD    = (const float*)d_in[3];
    const float* alpha = (const float*)d_in[4];
    const float* w_v   = (const float*)d_in[5];
    const float* w_t   = (const float*)d_in[6];
    const float* b_v   = (const float*)d_in[7];
    const float* b_t   = (const float*)d_in[8];
    float* out = (float*)d_out;
    float* ws  = (float*)d_ws;

    if (ws_size >= WS_PACK_BYTES) {
        alnn_pack<<<450, 256, 0, stream>>>(X, T, M, PD, w_v, (const float4*)w_t, b_t, ws);
        alnn_main2<<<252, 512, 0, stream>>>(ws, alpha, b_v, out);
    } else {
        alnn_fused_kernel<<<NB * NK, 256, 0, stream>>>(
            X, T, M, PD, alpha, w_v, (const float4*)w_t, b_v, b_t, out);
    }
}